// Round 10
// baseline (375.201 us; speedup 1.0000x reference)
//
#include <hip/hip_runtime.h>
#include <hip/hip_fp16.h>
#include <hip/hip_cooperative_groups.h>

namespace cg = cooperative_groups;

// imgs (8,3,1024,1024) fp32, z (1e6,2) fp32 -> out (8,2) fp32.
// R21 (this round): single cooperative kernel = zero + hist + sweep.
//   R20 left all kernels under the 58.6us harness fill; remaining cost is
//   dispatch boundaries + zero overlap between hist's atomic drain (retire
//   -bound, ~20 G packets/s, low read-BW use) and sweep's ~108 MB of reads.
//   Fusion: 1024 blocks x 256 thr (launch_bounds(256,4) -> 4 blocks/CU
//   guaranteed co-resident), grid.sync() between phases. First sweep tile's
//   18 image loads are ISSUED BEFORE the second grid.sync -> they stream
//   while the grid-wide atomic drain finishes. Both tiles accumulate in
//   registers; ONE 16-lane out-atomic per block (1024 packets total).
//   Runtime fallback to the R20 3-dispatch path if cooperative launch is
//   rejected. hist encoding unchanged: 1 u64 atomic per point
//   {cnt:12b | sumU:26b | sumV:26b}, u/v quantized 2^-20.
//   Per cell: sum(gc0) = cnt*Dy + sumU*M ; sum(gc1) = cnt*Dx + sumV*M.

#define NYX 1024
#define NPIX (NYX * NYX)
#define BATCH 8
#define CH 3
#define QSCALE 1048576.0f                            // 2^20
#define QINV   (1.0f / 1048576.0f)
#define SWEEP_TILES 2048                             // 2 rows x 256 cols each

// ---- shared device helpers ----
__device__ __forceinline__ void hist_pt(float zy, float zx,
                                        unsigned long long* __restrict__ hist)
{
    float x0y = zy * (float)(NYX - 1);
    float x0x = zx * (float)(NYX - 1);
    bool oob = (x0y < 0.0f) || (x0y > (float)(NYX - 1)) ||
               (x0x < 0.0f) || (x0x > (float)(NYX - 1));
    if (oob) return;                                 // contributes nothing
    int yg = min((int)x0y, NYX - 2);
    int xg = min((int)x0x, NYX - 2);
    float u = x0x - (float)xg;
    float v = x0y - (float)yg;
    unsigned qu = (unsigned)(u * QSCALE + 0.5f);     // <= 2^20, fits 26b
    unsigned qv = (unsigned)(v * QSCALE + 0.5f);
    unsigned long long key = (1ULL << 52) |
                             ((unsigned long long)qu << 26) |
                             (unsigned long long)qv;
    atomicAdd(&hist[(yg << 10) + xg], key);          // fire-and-forget
}

__device__ __forceinline__ void dec_cell(unsigned lo, unsigned hi,
                                         float& cnt, float& su, float& sv)
{
    cnt = (float)(hi >> 20);                         // bits 52..63
    su  = (float)((lo >> 26) | ((hi & 0xFFFFFu) << 6)) * QINV;  // bits 26..51
    sv  = (float)(lo & 0x3FFFFFFu) * QINV;           // bits 0..25
}

struct Tile { int y0, x0, xe, yr1, yr2; };

__device__ __forceinline__ Tile tile_of(int vb) {
    // XCD-preserving bijection on [0,2048): vb%8 = XCD chunk, y-major inside
    int L = ((vb & 7) << 8) | (vb >> 3);
    Tile T;
    T.y0  = (L & 511) << 1;
    T.x0  = (L >> 9) << 8;
    T.xe  = min(T.x0 + 256, NYX - 1);
    T.yr1 = min(T.y0 + 1, NYX - 1);
    T.yr2 = min(T.y0 + 2, NYX - 1);
    return T;
}

__device__ __forceinline__ void load_tile(const float* __restrict__ imgs,
                                          const Tile& T, int l, int g,
                                          float4 v[18], float edge[6])
{
    int yr[3] = { T.y0, T.yr1, T.yr2 };
#pragma unroll
    for (int r = 0; r < 3; ++r) {
#pragma unroll
        for (int bl = 0; bl < 2; ++bl) {
            int b = 2 * g + bl;
            size_t q = (size_t)yr[r] * NYX + T.x0;
#pragma unroll
            for (int c = 0; c < CH; ++c)
                v[r * 6 + bl * 3 + c] =
                    ((const float4*)(imgs + (size_t)(b * CH + c) * NPIX + q))[l];
        }
    }
#pragma unroll
    for (int i = 0; i < 6; ++i) edge[i] = 0.0f;
    if (l == 63) {
#pragma unroll
        for (int r = 0; r < 3; ++r) {
#pragma unroll
            for (int bl = 0; bl < 2; ++bl) {
                int b = 2 * g + bl;
                size_t qe = (size_t)yr[r] * NYX + T.xe;
                edge[r * 2 + bl] = imgs[(size_t)(b * CH + 0) * NPIX + qe] +
                                   imgs[(size_t)(b * CH + 1) * NPIX + qe] +
                                   imgs[(size_t)(b * CH + 2) * NPIX + qe];
            }
        }
    }
}

__device__ __forceinline__ void tile_accum(const Tile& T,
                                           const uint4* __restrict__ hist2,
                                           const float4 v[18],
                                           const float edge[6], int l,
                                           float acc0[2], float acc1[2])
{
    // hist rows y0, y0+1, cols x0+4l..x0+4l+3 (u64 pairs as uint4)
    size_t hb0 = ((size_t)T.y0 * NYX + T.x0 + 4 * l) >> 1;
    size_t hb1 = ((size_t)(T.y0 + 1) * NYX + T.x0 + 4 * l) >> 1;
    uint4 h0a = hist2[hb0], h0b = hist2[hb0 + 1];
    uint4 h1a = hist2[hb1], h1b = hist2[hb1 + 1];

    // channel-sum -> S[r][bl][0..3] (cols 4l..4l+3)
    float S[3][2][4];
#pragma unroll
    for (int r = 0; r < 3; ++r) {
#pragma unroll
        for (int bl = 0; bl < 2; ++bl) {
            float4 a0 = v[r * 6 + bl * 3 + 0];
            float4 a1 = v[r * 6 + bl * 3 + 1];
            float4 a2 = v[r * 6 + bl * 3 + 2];
            S[r][bl][0] = a0.x + a1.x + a2.x;
            S[r][bl][1] = a0.y + a1.y + a2.y;
            S[r][bl][2] = a0.z + a1.z + a2.z;
            S[r][bl][3] = a0.w + a1.w + a2.w;
        }
    }

    // next-column S via cross-lane shuffle (lane 63 <- strip edge)
    float sp[3][2];
#pragma unroll
    for (int r = 0; r < 3; ++r) {
#pragma unroll
        for (int bl = 0; bl < 2; ++bl) {
            float nx = __shfl_down(S[r][bl][0], 1, 64);
            sp[r][bl] = (l == 63) ? edge[r * 2 + bl] : nx;
        }
    }

    float cnt[2][4], su[2][4], sv[2][4];
    dec_cell(h0a.x, h0a.y, cnt[0][0], su[0][0], sv[0][0]);
    dec_cell(h0a.z, h0a.w, cnt[0][1], su[0][1], sv[0][1]);
    dec_cell(h0b.x, h0b.y, cnt[0][2], su[0][2], sv[0][2]);
    dec_cell(h0b.z, h0b.w, cnt[0][3], su[0][3], sv[0][3]);
    dec_cell(h1a.x, h1a.y, cnt[1][0], su[1][0], sv[1][0]);
    dec_cell(h1a.z, h1a.w, cnt[1][1], su[1][1], sv[1][1]);
    dec_cell(h1b.x, h1b.y, cnt[1][2], su[1][2], sv[1][2]);
    dec_cell(h1b.z, h1b.w, cnt[1][3], su[1][3], sv[1][3]);

#pragma unroll
    for (int bl = 0; bl < 2; ++bl) {
#pragma unroll
        for (int k = 0; k < 2; ++k) {
#pragma unroll
            for (int j = 0; j < 4; ++j) {
                float c00 = S[k][bl][j];
                float c01 = (j < 3) ? S[k][bl][j + 1] : sp[k][bl];
                float c10 = S[k + 1][bl][j];
                float c11 = (j < 3) ? S[k + 1][bl][j + 1] : sp[k + 1][bl];
                float Dy = c10 - c00;
                float Dx = c01 - c00;
                float Mm = (c11 - c01) - Dy;
                acc0[bl] += cnt[k][j] * Dy + su[k][j] * Mm;
                acc1[bl] += cnt[k][j] * Dx + sv[k][j] * Mm;
            }
        }
    }
}

// ---- the fused cooperative kernel ----
__global__ __launch_bounds__(256, 4) void fused_kernel(
    const float* __restrict__ imgs, const float* __restrict__ z,
    unsigned long long* __restrict__ hist, float* __restrict__ out, int npts)
{
    cg::grid_group grid = cg::this_grid();
    int bid = blockIdx.x, t = threadIdx.x, nb = gridDim.x;
    int l = t & 63, g = t >> 6;
    int nthr = nb * 256;
    int tid = bid * 256 + t;

    // phase 0: zero hist (8 MB) + out[16]
    uint4* h4 = (uint4*)hist;
    for (int j = tid; j < NPIX / 2; j += nthr)
        h4[j] = make_uint4(0u, 0u, 0u, 0u);
    if (bid == 0 && t < 16) out[t] = 0.0f;
    grid.sync();

    // phase 1: histogram (1 u64 atomic per point)
    int npairs = npts >> 1;
    for (int i = tid; i < npairs; i += nthr) {
        float4 zz = ((const float4*)z)[i];
        hist_pt(zz.x, zz.y, hist);
        hist_pt(zz.z, zz.w, hist);
    }
    if ((npts & 1) && bid == 0 && t == 0)
        hist_pt(z[2 * npts - 2], z[2 * npts - 1], hist);

    // prefetch first sweep tile's image data (hist-independent): these reads
    // stream while the grid-wide atomic drain + barrier completes
    Tile T0 = tile_of(bid);
    float4 v[18];
    float  edge[6];
    load_tile(imgs, T0, l, g, v, edge);
    grid.sync();

    // phase 2: sweep all 2048 tiles (2 per block at nb=1024)
    const uint4* hist2 = (const uint4*)hist;
    float acc0[2] = {0.f, 0.f}, acc1[2] = {0.f, 0.f};
    tile_accum(T0, hist2, v, edge, l, acc0, acc1);
    for (int vb = bid + nb; vb < SWEEP_TILES; vb += nb) {
        Tile T = tile_of(vb);
        load_tile(imgs, T, l, g, v, edge);
        tile_accum(T, hist2, v, edge, l, acc0, acc1);
    }

    // epilogue: wave reduce -> 64 B LDS -> ONE 16-lane atomic per block
#pragma unroll
    for (int off = 32; off > 0; off >>= 1) {
        acc0[0] += __shfl_down(acc0[0], off, 64);
        acc1[0] += __shfl_down(acc1[0], off, 64);
        acc0[1] += __shfl_down(acc0[1], off, 64);
        acc1[1] += __shfl_down(acc1[1], off, 64);
    }
    __shared__ float sred[4][4];
    if (l == 0) {
        sred[g][0] = acc0[0];
        sred[g][1] = acc1[0];
        sred[g][2] = acc0[1];
        sred[g][3] = acc1[1];
    }
    __syncthreads();
    if (t < 16)
        atomicAdd(&out[t], sred[t >> 2][t & 3]);
}

// ---- fallback B (R20 3-dispatch path) if cooperative launch rejected ----
__global__ __launch_bounds__(256) void hist_kernel(
    const float* __restrict__ z, unsigned long long* __restrict__ hist,
    float* __restrict__ out, int npts)
{
    int i = blockIdx.x * 256 + threadIdx.x;
    if (blockIdx.x == 0 && threadIdx.x < 16)
        out[threadIdx.x] = 0.0f;
    int npairs = npts >> 1;
    if (i < npairs) {
        float4 zz = ((const float4*)z)[i];
        hist_pt(zz.x, zz.y, hist);
        hist_pt(zz.z, zz.w, hist);
    } else if (i == npairs && (npts & 1)) {
        hist_pt(z[2 * npts - 2], z[2 * npts - 1], hist);
    }
}

__global__ __launch_bounds__(256, 4) void sweep_kernel(
    const float* __restrict__ imgs, const uint4* __restrict__ hist2,
    float* __restrict__ out)
{
    int t = threadIdx.x, l = t & 63, g = t >> 6;
    Tile T = tile_of(blockIdx.x);
    float4 v[18];
    float  edge[6];
    load_tile(imgs, T, l, g, v, edge);
    float acc0[2] = {0.f, 0.f}, acc1[2] = {0.f, 0.f};
    tile_accum(T, hist2, v, edge, l, acc0, acc1);
#pragma unroll
    for (int off = 32; off > 0; off >>= 1) {
        acc0[0] += __shfl_down(acc0[0], off, 64);
        acc1[0] += __shfl_down(acc1[0], off, 64);
        acc0[1] += __shfl_down(acc0[1], off, 64);
        acc1[1] += __shfl_down(acc1[1], off, 64);
    }
    __shared__ float sred[4][4];
    if (l == 0) {
        sred[g][0] = acc0[0];
        sred[g][1] = acc1[0];
        sred[g][2] = acc0[1];
        sred[g][3] = acc1[1];
    }
    __syncthreads();
    if (t < 16)
        atomicAdd(&out[t], sred[t >> 2][t & 3]);
}

// ---- fallback A (round-1 unsorted path) if ws is too small ----
__global__ void zero_out_kernel(float* __restrict__ out) {
    int i = threadIdx.x;
    if (i < 16) out[i] = 0.0f;
}

__global__ __launch_bounds__(256) void interp_grad_kernel(
    const float* __restrict__ imgs, const float* __restrict__ z,
    float* __restrict__ out, int npts)
{
    int p = blockIdx.x * blockDim.x + threadIdx.x;
    float acc0[BATCH];
    float acc1[BATCH];
#pragma unroll
    for (int b = 0; b < BATCH; ++b) { acc0[b] = 0.0f; acc1[b] = 0.0f; }
    if (p < npts) {
        float2 zz = ((const float2*)z)[p];
        float x0y = zz.x * (float)(NYX - 1);
        float x0x = zz.y * (float)(NYX - 1);
        bool oob = (x0y < 0.0f) || (x0y > (float)(NYX - 1)) ||
                   (x0x < 0.0f) || (x0x > (float)(NYX - 1));
        if (!oob) {
            int yg = min((int)floorf(x0y), NYX - 2);
            int xg = min((int)floorf(x0x), NYX - 2);
            float fy = (float)yg - x0y;
            float fx = (float)xg - x0x;
            const float* base = imgs + (size_t)yg * NYX + xg;
#pragma unroll
            for (int b = 0; b < BATCH; ++b) {
#pragma unroll
                for (int c = 0; c < CH; ++c) {
                    const float* pl = base + (size_t)(b * CH + c) * (size_t)NPIX;
                    float g00 = pl[0];
                    float g01 = pl[1];
                    float g10 = pl[NYX];
                    float g11 = pl[NYX + 1];
                    float a1 = g10 - g00;
                    float a2 = g11 - g01;
                    float a3 = g01 - g00;
                    float d  = a1 - a2;
                    acc0[b] += d * fx + a1;
                    acc1[b] += d * fy + a3;
                }
            }
        }
    }
#pragma unroll
    for (int b = 0; b < BATCH; ++b) {
#pragma unroll
        for (int off = 32; off > 0; off >>= 1) {
            acc0[b] += __shfl_down(acc0[b], off, 64);
            acc1[b] += __shfl_down(acc1[b], off, 64);
        }
    }
    __shared__ float sred2[4][16];
    int lane = threadIdx.x & 63;
    int wave = threadIdx.x >> 6;
    if (lane == 0) {
#pragma unroll
        for (int b = 0; b < BATCH; ++b) {
            sred2[wave][2 * b + 0] = acc0[b];
            sred2[wave][2 * b + 1] = acc1[b];
        }
    }
    __syncthreads();
    if (threadIdx.x < 16) {
        float s = sred2[0][threadIdx.x] + sred2[1][threadIdx.x] +
                  sred2[2][threadIdx.x] + sred2[3][threadIdx.x];
        atomicAdd(&out[threadIdx.x], s);
    }
}

extern "C" void kernel_launch(void* const* d_in, const int* in_sizes, int n_in,
                              void* d_out, int out_size, void* d_ws, size_t ws_size,
                              hipStream_t stream) {
    const float* imgs = (const float*)d_in[0];
    const float* z    = (const float*)d_in[1];
    float* out        = (float*)d_out;
    int npts = in_sizes[1] / 2;

    size_t ws_need = (size_t)NPIX * 8;               // 8 MB u64 hist

    if (ws_size < ws_need) {
        int blocks = (npts + 255) / 256;
        zero_out_kernel<<<1, 64, 0, stream>>>(out);
        interp_grad_kernel<<<blocks, 256, 0, stream>>>(imgs, z, out, npts);
        return;
    }

    unsigned long long* hist = (unsigned long long*)d_ws;

    // single fused cooperative kernel: 1024 blocks co-resident by
    // construction (launch_bounds(256,4) -> 4 blocks/CU x 256 CUs)
    void* args[] = { (void*)&imgs, (void*)&z, (void*)&hist,
                     (void*)&out, (void*)&npts };
    hipError_t e = hipLaunchCooperativeKernel(
        (const void*)fused_kernel, dim3(1024), dim3(256), args, 0, stream);

    if (e != hipSuccess) {                           // fallback: R20 path
        int npairs = npts >> 1;
        int hist_blocks = (npairs + 256) / 256;
        hipMemsetAsync(d_ws, 0, ws_need, stream);
        hist_kernel<<<hist_blocks, 256, 0, stream>>>(z, hist, out, npts);
        sweep_kernel<<<SWEEP_TILES, 256, 0, stream>>>(
            imgs, (const uint4*)hist, out);
    }
}

// Round 11
// 218.099 us; speedup vs baseline: 1.7203x; 1.7203x over previous
//
#include <hip/hip_runtime.h>
#include <hip/hip_fp16.h>

// imgs (8,3,1024,1024) fp32, z (1e6,2) fp32 -> out (8,2) fp32.
// R22 (this round): revert to R15 (session best, 189.0) + ONE change:
//   precompute __launch_bounds__(256,4) -> (256,6). R15 counters showed
//   precompute latency-bound (2.2 TB/s, 31% occupancy, VALUBusy 6.5%) and
//   capped at 4 blocks/CU by the DECLARATION, not by resources: LDS
//   24.7 KB x 6 = 148 <= 160 KB, VGPR 60 <= 85 (512/6). 6 resident blocks
//   give 1.5x the waves to cover each block's barrier/vmcnt stalls.
//   (R21 post-mortem: cooperative fusion = 256 us, worse than the sum of
//   its parts — grid.sync fence/spin + halved hist parallelism; abandoned.)
// Structure (R15): precompute ROWS=2, 18 upfront float4 loads, fp32 S rows
// in LDS, sS/stage union (24.7 KB), 5 barriers, XCD swizzle; gather 2-pair
// unroll; fused atomic reduce (out zeroed by precompute block 0).
// T record per pixel: 64 B = uint4[4]: [0]=Dy(8 half), [1]=Dx, [2]=M,
// [3]=pad -> exactly one cache line per gathered point.

#define NYX 1024
#define NPIX (NYX * NYX)
#define BATCH 8
#define CH 3
#define GB 1024                                  // gather blocks
#define SW(i) ((i) ^ (((i) >> 4) & 7))           // stage swizzle (involution)
#define EDGEI 6144                               // sEdge float index (24576 B)

__device__ __forceinline__ unsigned pk2(float a, float b) {
    __half2 h = __floats2half2_rn(a, b);
    return *(unsigned*)&h;
}

__device__ __forceinline__ float4 add4(float4 a, float4 b, float4 c) {
    return make_float4(a.x + b.x + c.x, a.y + b.y + c.y,
                       a.z + b.z + c.z, a.w + b.w + c.w);
}

__global__ __launch_bounds__(256, 6) void precompute_kernel(
    const float* __restrict__ imgs, uint4* __restrict__ T,
    float* __restrict__ out)
{
    // 2048 blocks. XCD swizzle: chunk of 256 logical blocks per XCD,
    // y-major within a strip so adjacent y-groups (sharing boundary row
    // y0+2) are dispatched back-to-back on the same XCD.
    int bid0  = blockIdx.x;
    int L     = ((bid0 & 7) << 8) | (bid0 >> 3); // bijective on [0,2048)
    int ygrp  = L & 511;
    int strip = L >> 9;                          // 0..3
    int y0    = ygrp << 1;
    int x0    = strip << 8;
    int t     = threadIdx.x;
    int lane  = t & 63;
    int g     = t >> 6;                          // group -> batches 2g,2g+1
    int xe    = min(x0 + 256, NYX - 1);          // strip-edge col

    if (bid0 == 0 && t < 16) out[t] = 0.0f;      // zero for gather's atomics

    // union: phase 1 = sS (24 rows x 256 f32 = 24576 B) + sEdge (24 f32);
    //        phase 2 = stage (1024 x uint4 = 16384 B). 24704 B total.
    __shared__ __align__(16) char smem[24704];
    float* sS    = (float*)smem;                 // row rr=b*3+r, col 0..255
    float* sEdge = (float*)smem + EDGEI;         // [rr] = col-256 value
    uint4* stage = (uint4*)smem;

    int yr0 = y0;
    int yr1 = min(y0 + 1, NYX - 1);
    int yr2 = min(y0 + 2, NYX - 1);              // row 1023 records unread
    size_t q[3] = { (size_t)yr0 * NYX + x0,
                    (size_t)yr1 * NYX + x0,
                    (size_t)yr2 * NYX + x0 };

    // 18 independent float4 loads (3 rows x 2 batches x 3 channels)
    float4 v[18];
#pragma unroll
    for (int r = 0; r < 3; ++r) {
#pragma unroll
        for (int bl = 0; bl < 2; ++bl) {
#pragma unroll
            for (int c = 0; c < CH; ++c) {
                const float* pl = imgs + (size_t)((2 * g + bl) * CH + c) * NPIX;
                v[r * 6 + bl * 3 + c] = ((const float4*)(pl + q[r]))[lane];
            }
        }
    }
    float edge[6] = {0.f, 0.f, 0.f, 0.f, 0.f, 0.f};
    if (lane == 63) {
        size_t qe[3] = { (size_t)yr0 * NYX + xe,
                         (size_t)yr1 * NYX + xe,
                         (size_t)yr2 * NYX + xe };
#pragma unroll
        for (int r = 0; r < 3; ++r) {
#pragma unroll
            for (int bl = 0; bl < 2; ++bl) {
#pragma unroll
                for (int c = 0; c < CH; ++c) {
                    const float* pl = imgs + (size_t)((2 * g + bl) * CH + c) * NPIX;
                    edge[r * 2 + bl] += pl[qe[r]];
                }
            }
        }
    }

    // channel-sum -> 3 S rows per batch (stride-256: f4 writes conflict-free)
#pragma unroll
    for (int r = 0; r < 3; ++r) {
#pragma unroll
        for (int bl = 0; bl < 2; ++bl) {
            int b = 2 * g + bl;
            float4 s = add4(v[r * 6 + bl * 3 + 0], v[r * 6 + bl * 3 + 1],
                            v[r * 6 + bl * 3 + 2]);
            *(float4*)&sS[(b * 3 + r) * 256 + 4 * lane] = s;
            if (lane == 63) sEdge[b * 3 + r] = edge[r * 2 + bl];
        }
    }
    __syncthreads();                             // B1: sS ready

    // records for BOTH rows into registers (48 VGPRs), then sS is dead
    float Dy[2][BATCH], Dx[2][BATCH], Mm[2][BATCH];
#pragma unroll
    for (int b = 0; b < BATCH; ++b) {
        float s[3], sp[3];
#pragma unroll
        for (int r = 0; r < 3; ++r) {
            int rr = b * 3 + r;
            s[r]  = sS[rr * 256 + t];
            sp[r] = (t < 255) ? sS[rr * 256 + t + 1] : sEdge[rr];
        }
        Dy[0][b] = s[1] - s[0];
        Dx[0][b] = sp[0] - s[0];
        Mm[0][b] = (sp[1] - sp[0]) - Dy[0][b];
        Dy[1][b] = s[2] - s[1];
        Dx[1][b] = sp[1] - s[1];
        Mm[1][b] = (sp[2] - sp[1]) - Dy[1][b];
    }
    __syncthreads();                             // B2: sS reads done, reuse LDS

#pragma unroll
    for (int k = 0; k < 2; ++k) {
        stage[SW(t * 4 + 0)] =
            make_uint4(pk2(Dy[k][0], Dy[k][1]), pk2(Dy[k][2], Dy[k][3]),
                       pk2(Dy[k][4], Dy[k][5]), pk2(Dy[k][6], Dy[k][7]));
        stage[SW(t * 4 + 1)] =
            make_uint4(pk2(Dx[k][0], Dx[k][1]), pk2(Dx[k][2], Dx[k][3]),
                       pk2(Dx[k][4], Dx[k][5]), pk2(Dx[k][6], Dx[k][7]));
        stage[SW(t * 4 + 2)] =
            make_uint4(pk2(Mm[k][0], Mm[k][1]), pk2(Mm[k][2], Mm[k][3]),
                       pk2(Mm[k][4], Mm[k][5]), pk2(Mm[k][6], Mm[k][7]));
        stage[SW(t * 4 + 3)] = make_uint4(0u, 0u, 0u, 0u);
        __syncthreads();                         // stage ready

        // coalesced copy-out: 1024 consecutive uint4 (16 KB window, full lines)
        size_t base4 = ((size_t)(y0 + k) * NYX + x0) * 4;
#pragma unroll
        for (int i = 0; i < 4; ++i)
            T[base4 + i * 256 + t] = stage[SW(i * 256 + t)];
        if (k == 0) __syncthreads();             // stage reuse for row 1
    }
}

struct PtSetup {
    const uint4* t4;
    float u, v, s;
};

__device__ __forceinline__ PtSetup setup_pt(float zy, float zx,
                                            const uint4* __restrict__ T) {
    PtSetup r;
    float x0y = zy * (float)(NYX - 1);
    float x0x = zx * (float)(NYX - 1);
    bool oob = (x0y < 0.0f) || (x0y > (float)(NYX - 1)) ||
               (x0x < 0.0f) || (x0x > (float)(NYX - 1));
    float cy = fminf(fmaxf(x0y, 0.0f), (float)(NYX - 1));
    float cx = fminf(fmaxf(x0x, 0.0f), (float)(NYX - 1));
    int yg = min((int)cy, NYX - 2);
    int xg = min((int)cx, NYX - 2);
    r.u = cx - (float)xg;
    r.v = cy - (float)yg;
    r.s = oob ? 0.0f : 1.0f;
    r.t4 = T + ((size_t)yg * NYX + xg) * 4;
    return r;
}

__device__ __forceinline__ void accum_pt(PtSetup P, uint4 rDy, uint4 rDx,
                                         uint4 rM, float* acc0, float* acc1) {
    const __half2* hDy = (const __half2*)&rDy;
    const __half2* hDx = (const __half2*)&rDx;
    const __half2* hM  = (const __half2*)&rM;
#pragma unroll
    for (int j = 0; j < 4; ++j) {
        float2 dy = __half22float2(hDy[j]);
        float2 dx = __half22float2(hDx[j]);
        float2 m  = __half22float2(hM[j]);
        acc0[2 * j + 0] += P.s * fmaf(P.u, m.x, dy.x);
        acc0[2 * j + 1] += P.s * fmaf(P.u, m.y, dy.y);
        acc1[2 * j + 0] += P.s * fmaf(P.v, m.x, dx.x);
        acc1[2 * j + 1] += P.s * fmaf(P.v, m.y, dx.y);
    }
}

__global__ __launch_bounds__(256, 4) void gather_kernel(
    const float* __restrict__ z, const uint4* __restrict__ T,
    float* __restrict__ out, int npts)
{
    float acc0[BATCH];
    float acc1[BATCH];
#pragma unroll
    for (int b = 0; b < BATCH; ++b) { acc0[b] = 0.0f; acc1[b] = 0.0f; }

    const float4* z4 = (const float4*)z;
    int npairs = npts >> 1;
    int stride = gridDim.x * blockDim.x;
    int tid = blockIdx.x * blockDim.x + threadIdx.x;

    // 2 pairs (4 points) per iteration: 2 z-loads + 12 record loads in flight
    for (int i = tid; i < npairs; i += 2 * stride) {
        int i2 = i + stride;
        bool has2 = i2 < npairs;
        float4 za = z4[i];
        float4 zb = z4[has2 ? i2 : i];           // clamped dup, zeroed below
        PtSetup A = setup_pt(za.x, za.y, T);
        PtSetup B = setup_pt(za.z, za.w, T);
        PtSetup C = setup_pt(zb.x, zb.y, T);
        PtSetup D = setup_pt(zb.z, zb.w, T);
        if (!has2) { C.s = 0.0f; D.s = 0.0f; }
        uint4 aDy = A.t4[0], aDx = A.t4[1], aM = A.t4[2];
        uint4 bDy = B.t4[0], bDx = B.t4[1], bM = B.t4[2];
        uint4 cDy = C.t4[0], cDx = C.t4[1], cM = C.t4[2];
        uint4 dDy = D.t4[0], dDx = D.t4[1], dM = D.t4[2];
        accum_pt(A, aDy, aDx, aM, acc0, acc1);
        accum_pt(B, bDy, bDx, bM, acc0, acc1);
        accum_pt(C, cDy, cDx, cM, acc0, acc1);
        accum_pt(D, dDy, dDx, dM, acc0, acc1);
    }

    // odd-npts tail (not taken for npts = 1e6)
    if ((npts & 1) && blockIdx.x == 0 && threadIdx.x == 0) {
        float zy = z[2 * (npts - 1)], zx = z[2 * (npts - 1) + 1];
        PtSetup A = setup_pt(zy, zx, T);
        uint4 aDy = A.t4[0], aDx = A.t4[1], aM = A.t4[2];
        accum_pt(A, aDy, aDx, aM, acc0, acc1);
    }

#pragma unroll
    for (int b = 0; b < BATCH; ++b) {
#pragma unroll
        for (int off = 32; off > 0; off >>= 1) {
            acc0[b] += __shfl_down(acc0[b], off, 64);
            acc1[b] += __shfl_down(acc1[b], off, 64);
        }
    }

    __shared__ float sred[4][16];
    int lane = threadIdx.x & 63;
    int wave = threadIdx.x >> 6;
    if (lane == 0) {
#pragma unroll
        for (int b = 0; b < BATCH; ++b) {
            sred[wave][2 * b + 0] = acc0[b];
            sred[wave][2 * b + 1] = acc1[b];
        }
    }
    __syncthreads();
    if (threadIdx.x < 16) {
        float s = sred[0][threadIdx.x] + sred[1][threadIdx.x] +
                  sred[2][threadIdx.x] + sred[3][threadIdx.x];
        atomicAdd(&out[threadIdx.x], s);         // out zeroed by precompute
    }
}

// ---- fallback (round-1 unsorted path) if ws is too small ----
__global__ void zero_out_kernel(float* __restrict__ out) {
    int i = threadIdx.x;
    if (i < 16) out[i] = 0.0f;
}

__global__ __launch_bounds__(256) void interp_grad_kernel(
    const float* __restrict__ imgs, const float* __restrict__ z,
    float* __restrict__ out, int npts)
{
    int p = blockIdx.x * blockDim.x + threadIdx.x;
    float acc0[BATCH];
    float acc1[BATCH];
#pragma unroll
    for (int b = 0; b < BATCH; ++b) { acc0[b] = 0.0f; acc1[b] = 0.0f; }
    if (p < npts) {
        float2 zz = ((const float2*)z)[p];
        float x0y = zz.x * (float)(NYX - 1);
        float x0x = zz.y * (float)(NYX - 1);
        bool oob = (x0y < 0.0f) || (x0y > (float)(NYX - 1)) ||
                   (x0x < 0.0f) || (x0x > (float)(NYX - 1));
        if (!oob) {
            int yg = min((int)floorf(x0y), NYX - 2);
            int xg = min((int)floorf(x0x), NYX - 2);
            float fy = (float)yg - x0y;
            float fx = (float)xg - x0x;
            const float* base = imgs + (size_t)yg * NYX + xg;
#pragma unroll
            for (int b = 0; b < BATCH; ++b) {
#pragma unroll
                for (int c = 0; c < CH; ++c) {
                    const float* pl = base + (size_t)(b * CH + c) * (size_t)NPIX;
                    float g00 = pl[0];
                    float g01 = pl[1];
                    float g10 = pl[NYX];
                    float g11 = pl[NYX + 1];
                    float a1 = g10 - g00;
                    float a2 = g11 - g01;
                    float a3 = g01 - g00;
                    float d  = a1 - a2;
                    acc0[b] += d * fx + a1;
                    acc1[b] += d * fy + a3;
                }
            }
        }
    }
#pragma unroll
    for (int b = 0; b < BATCH; ++b) {
#pragma unroll
        for (int off = 32; off > 0; off >>= 1) {
            acc0[b] += __shfl_down(acc0[b], off, 64);
            acc1[b] += __shfl_down(acc1[b], off, 64);
        }
    }
    __shared__ float sred[4][16];
    int lane = threadIdx.x & 63;
    int wave = threadIdx.x >> 6;
    if (lane == 0) {
#pragma unroll
        for (int b = 0; b < BATCH; ++b) {
            sred[wave][2 * b + 0] = acc0[b];
            sred[wave][2 * b + 1] = acc1[b];
        }
    }
    __syncthreads();
    if (threadIdx.x < 16) {
        float s = sred[0][threadIdx.x] + sred[1][threadIdx.x] +
                  sred[2][threadIdx.x] + sred[3][threadIdx.x];
        atomicAdd(&out[threadIdx.x], s);
    }
}

extern "C" void kernel_launch(void* const* d_in, const int* in_sizes, int n_in,
                              void* d_out, int out_size, void* d_ws, size_t ws_size,
                              hipStream_t stream) {
    const float* imgs = (const float*)d_in[0];
    const float* z    = (const float*)d_in[1];
    float* out        = (float*)d_out;
    int npts = in_sizes[1] / 2;

    size_t ws_need = (size_t)NPIX * 64;          // 64 MB T table

    if (ws_size < ws_need) {
        int blocks = (npts + 255) / 256;
        zero_out_kernel<<<1, 64, 0, stream>>>(out);
        interp_grad_kernel<<<blocks, 256, 0, stream>>>(imgs, z, out, npts);
        return;
    }

    uint4* T = (uint4*)d_ws;

    precompute_kernel<<<(NYX / 2) * 4, 256, 0, stream>>>(imgs, T, out);
    gather_kernel<<<GB, 256, 0, stream>>>(z, T, out, npts);
}